// Round 4
// baseline (12183.904 us; speedup 1.0000x reference)
//
#include <hip/hip_runtime.h>
#include <stdint.h>

// LSTM: SEQ=4096, HIDDEN=2048, INPUT=128. Persistent cooperative kernel.
// R12 = R11 (R8 topology: 256 blocks x 512 thr, 1 block/CU; f16x2 weights
// + v_dot2_f32_f16, verified absmax 0.0) + 2-deep PIPELINED POLL:
//  - two register streams A/B of 8x global_load_dwordx4 each; issue both,
//    then alternate s_waitcnt vmcnt(8) (retires only the 8 OLDEST = the
//    stream being checked) -> tag-check -> reissue. Checks land every
//    ~L/2 instead of every L+check+sleep; s_sleep removed.
//  - rationale: R9 (XCD multicast, 2.9s) and R10 (128 blocks, 14ms)
//    proved the rendezvous is latency/quantization-bound, NOT
//    requester-queueing-bound. R11's compute shrink made the step SLOWER
//    (2.28->2.40us) -> step period locks to store-visibility + k*U
//    (poll-round quantization). Halving the check cadence attacks k*U.
//  - WAW safety: a stream is only reissued after its own vmcnt(8)
//    retirement; loop-exit leftovers are drained by an explicit
//    vmcnt(0) at the next poll entry. Rule #18: the vmcnt asm carries
//    "+v" on all 8 stream regs (def the check depends on) +
//    sched_barrier(0).
// Cross-replay staleness safe by exact-tag matching (stale p0 tag16=4096
// never equals an even want<=4094; stale p1 tag 4095 only matches want
// 4095 whose value is deterministic-identical across replays).
// ws layout (u32): [0,4096) hslots[2][HID]; [4096,4608) fbuf[256] u64.

#define SEQ   4096
#define NIN   128
#define HID   2048
#define NBLK  256
#define NTHR  512
#define UPB   8       // units per block = waves per block

typedef unsigned int u32x4 __attribute__((ext_vector_type(4)));
typedef _Float16 half2_t __attribute__((ext_vector_type(2)));

__device__ __forceinline__ uint64_t ld8_sys(const void* p) {
  uint64_t r;
  asm volatile("global_load_dwordx2 %0, %1, off sc0 sc1\n\t"
               "s_waitcnt vmcnt(0)"
               : "=v"(r) : "v"(p) : "memory");
  return r;
}
__device__ __forceinline__ void st4_sys(void* p, uint32_t v) {
  asm volatile("global_store_dword %0, %1, off sc0 sc1"
               :: "v"(p), "v"(v) : "memory");
}
__device__ __forceinline__ void st8_sys(void* p, uint64_t v) {
  asm volatile("global_store_dwordx2 %0, %1, off sc0 sc1"
               :: "v"(p), "v"(v) : "memory");
}

// f32 -> f16 bits (RNE) in low 16; f16 low bits -> f32
__device__ __forceinline__ uint32_t f32_to_f16lo(float x) {
  uint32_t r;
  asm("v_cvt_f16_f32 %0, %1" : "=v"(r) : "v"(x));
  return r & 0xFFFFu;
}
__device__ __forceinline__ float f16lo_to_f32(uint32_t u) {
  float r;
  asm("v_cvt_f32_f16 %0, %1" : "=v"(r) : "v"(u));
  return r;
}
__device__ __forceinline__ uint32_t pack_f16x2(float a, float b) {
  return f32_to_f16lo(a) | (f32_to_f16lo(b) << 16);
}
__device__ __forceinline__ half2_t as_h2(uint32_t u) {
  union { uint32_t u; half2_t h; } x; x.u = u; return x.h;
}

// packed f16 dot2 with f32 accumulate (verified bit-correct in R10/R11)
#if defined(__has_builtin)
#if __has_builtin(__builtin_amdgcn_fdot2)
#define HAVE_FDOT2 1
#endif
#endif
__device__ __forceinline__ float dot2(uint32_t w, uint32_t h, float acc) {
#ifdef HAVE_FDOT2
  return __builtin_amdgcn_fdot2(as_h2(w), as_h2(h), acc, false);
#else
  acc = fmaf(f16lo_to_f32(w & 0xFFFFu), f16lo_to_f32(h & 0xFFFFu), acc);
  acc = fmaf(f16lo_to_f32(w >> 16),     f16lo_to_f32(h >> 16),     acc);
  return acc;
#endif
}

// DPP full-wave (64-lane) sum; result valid in lane 63.
template <int CTRL>
__device__ __forceinline__ float dpp_add(float x) {
  int y = __builtin_amdgcn_update_dpp(0, __float_as_int(x), CTRL, 0xF, 0xF, true);
  return x + __int_as_float(y);
}
__device__ __forceinline__ float wave_reduce(float x) {
  x = dpp_add<0x111>(x);  // row_shr:1
  x = dpp_add<0x112>(x);  // row_shr:2
  x = dpp_add<0x114>(x);  // row_shr:4
  x = dpp_add<0x118>(x);  // row_shr:8
  x = dpp_add<0x142>(x);  // row_bcast:15
  x = dpp_add<0x143>(x);  // row_bcast:31
  return x;               // lane 63 holds the 64-lane sum
}

__device__ __forceinline__ float fast_sigmoid(float x) {
  return 1.0f / (1.0f + __expf(-x));
}
__device__ __forceinline__ float fast_tanh(float x) {
  return 1.0f - 2.0f / (1.0f + __expf(2.0f * x));
}

// quad-position swizzle (16B granularity), involution: q ^ ((q>>3)&7)
__device__ __forceinline__ int qpos(int q) { return q ^ ((q >> 3) & 7); }

// ---- 2-deep pipelined poll primitives ----
// issue one stream: 8x global_load_dwordx4, k-major contiguous 1KB each,
// NO wait. Early-clobber outputs (addr inputs live across all 8 loads).
__device__ __forceinline__ void poll_issue(const char* p0, const char* p1,
                                           u32x4& a0, u32x4& a1, u32x4& a2,
                                           u32x4& a3, u32x4& a4, u32x4& a5,
                                           u32x4& a6, u32x4& a7) {
  asm volatile(
      "global_load_dwordx4 %0, %8, off sc0 sc1\n\t"
      "global_load_dwordx4 %1, %8, off offset:1024 sc0 sc1\n\t"
      "global_load_dwordx4 %2, %8, off offset:2048 sc0 sc1\n\t"
      "global_load_dwordx4 %3, %8, off offset:3072 sc0 sc1\n\t"
      "global_load_dwordx4 %4, %9, off sc0 sc1\n\t"
      "global_load_dwordx4 %5, %9, off offset:1024 sc0 sc1\n\t"
      "global_load_dwordx4 %6, %9, off offset:2048 sc0 sc1\n\t"
      "global_load_dwordx4 %7, %9, off offset:3072 sc0 sc1"
      : "=&v"(a0), "=&v"(a1), "=&v"(a2), "=&v"(a3),
        "=&v"(a4), "=&v"(a5), "=&v"(a6), "=&v"(a7)
      : "v"(p0), "v"(p1) : "memory");
}
// wait until the 8 OLDEST outstanding VMEM ops retire (= the stream being
// checked; the other stream's 8 stay in flight). "+v" makes this a def of
// the stream regs so the following check can't be hoisted above it.
__device__ __forceinline__ void wait_oldest8(u32x4& a0, u32x4& a1, u32x4& a2,
                                             u32x4& a3, u32x4& a4, u32x4& a5,
                                             u32x4& a6, u32x4& a7) {
  asm volatile("s_waitcnt vmcnt(8)"
               : "+v"(a0), "+v"(a1), "+v"(a2), "+v"(a3),
                 "+v"(a4), "+v"(a5), "+v"(a6), "+v"(a7));
  __builtin_amdgcn_sched_barrier(0);
}
__device__ __forceinline__ bool check8(const u32x4& a0, const u32x4& a1,
                                       const u32x4& a2, const u32x4& a3,
                                       const u32x4& a4, const u32x4& a5,
                                       const u32x4& a6, const u32x4& a7,
                                       uint32_t want16) {
  bool ok = true;
#define CK4(A) ok &= ((A[0] >> 16) == want16) & ((A[1] >> 16) == want16) && \
                     ((A[2] >> 16) == want16) & ((A[3] >> 16) == want16);
  CK4(a0) CK4(a1) CK4(a2) CK4(a3) CK4(a4) CK4(a5) CK4(a6) CK4(a7)
#undef CK4
  return __all(ok) != 0;
}

__global__ __launch_bounds__(NTHR, 2) void lstm_persist(
    const float* __restrict__ X, const float* __restrict__ Wih,
    const float* __restrict__ Whh, const float* __restrict__ bih,
    const float* __restrict__ bhh, const float* __restrict__ Wlin,
    const float* __restrict__ blin, float* __restrict__ out,
    uint32_t* __restrict__ ws) {
  const int tid = threadIdx.x;
  const int blk = blockIdx.x;
  const int w   = tid >> 6;   // wave 0..7 -> owns hidden unit blk*8+w
  const int l   = tid & 63;   // lane; covers h-cols [l*32, l*32+32)

  uint32_t* hslots = ws;                         // [2][HID] {tag16|f16 h}
  uint64_t* fbuf   = (uint64_t*)(ws + 2 * HID);  // [NBLK] tagged finals

  // h staged as packed f16 PAIRS: 1024 u32 per parity, quad-swizzled.
  __shared__ __align__(16) uint32_t hp_lds[2][1024];
  volatile __shared__ uint32_t pub_lds[UPB];
  __shared__ float red[UPB];
  __shared__ float fin[NBLK];

  if (w == 0) __builtin_amdgcn_s_setprio(2);  // critical poll/publish wave

  // ---- init: weights into registers, packed f16x2 ----
  uint32_t whh[4][16];
  float wih[4][2];
  float bias4[4];
#pragma unroll
  for (int G = 0; G < 4; ++G) {
    const size_t Rg = (size_t)(G * HID + blk * UPB + w);
    const float4* src = (const float4*)(Whh + Rg * HID + l * 32);
#pragma unroll
    for (int m = 0; m < 8; ++m) {
      float4 v = src[m];
      whh[G][m * 2 + 0] = pack_f16x2(v.x, v.y);
      whh[G][m * 2 + 1] = pack_f16x2(v.z, v.w);
    }
    wih[G][0] = Wih[Rg * NIN + l * 2 + 0];
    wih[G][1] = Wih[Rg * NIN + l * 2 + 1];
    bias4[G]  = bih[Rg] + bhh[Rg];
  }
  const float wlin = Wlin[blk * UPB + w];

  if (tid < UPB) {
    // owner-init payload both parities (exact-tag matching makes stale
    // cross-replay data safe; see header).
    st4_sys(&hslots[0 * HID + blk * UPB + tid], 0u);           // tag0|f16(0)
    st4_sys(&hslots[1 * HID + blk * UPB + tid], 0xFFFF0000u);  // invalid
    pub_lds[tid] = 0xFFFF0000u;
  }
  if (tid == 0)
    st8_sys(&fbuf[blk], 0xFFFFFFFF00000000ull);
  __syncthreads();

  float cc = 0.0f;   // cell state (lane 63)
  float hl = 0.0f;   // last h (lane 63)

  // x prefetch: holds x_{t-1} for the upcoming step t
  float xp0 = X[(size_t)0 * NIN + l * 2 + 0];
  float xp1 = X[(size_t)0 * NIN + l * 2 + 1];

  for (int t = 1; t <= SEQ; ++t) {
    const uint32_t want16 = (uint32_t)(t - 1) & 0xFFFFu;
    const int par = (t - 1) & 1;
    const float x0 = xp0, x1 = xp1;

    // ---- wave 0: 2-deep pipelined poll of the whole 8KB payload ----
    if (w == 0) {
      const char* hp = (const char*)(hslots + (size_t)par * HID) + l * 16;
      u32x4 a0, a1, a2, a3, a4, a5, a6, a7;
      u32x4 b0, b1, b2, b3, b4, b5, b6, b7;
      // drain leftovers from last step's aborted stream (WAW safety)
      asm volatile("s_waitcnt vmcnt(0)" ::: "memory");
      poll_issue(hp, hp + 4096, a0, a1, a2, a3, a4, a5, a6, a7);
      poll_issue(hp, hp + 4096, b0, b1, b2, b3, b4, b5, b6, b7);
      bool useB = false;
      for (;;) {
        wait_oldest8(a0, a1, a2, a3, a4, a5, a6, a7);
        if (check8(a0, a1, a2, a3, a4, a5, a6, a7, want16)) { useB = false; break; }
        poll_issue(hp, hp + 4096, a0, a1, a2, a3, a4, a5, a6, a7);
        wait_oldest8(b0, b1, b2, b3, b4, b5, b6, b7);
        if (check8(b0, b1, b2, b3, b4, b5, b6, b7, want16)) { useB = true; break; }
        poll_issue(hp, hp + 4096, b0, b1, b2, b3, b4, b5, b6, b7);
      }
      // fan out tag-stripped f16 pairs. Load k, lane l holds units
      // u0=256k+4l..+3 -> pairs j0=128k+2l,+1 -> quad q=32k+(l>>1),
      // half (l&1). Swizzled by qpos(q) to spread compute-read banks.
      const int qbase = l >> 1;
      const int woff  = (l & 1) * 2;
#define FAN(A, K)                                                     \
      {                                                               \
        uint32_t pp0 = (A[0] & 0xFFFFu) | (A[1] << 16);               \
        uint32_t pp1 = (A[2] & 0xFFFFu) | (A[3] << 16);               \
        const int q = 32 * K + qbase;                                 \
        uint2 pv; pv.x = pp0; pv.y = pp1;                             \
        *(uint2*)&hp_lds[par][qpos(q) * 4 + woff] = pv;               \
      }
      if (!useB) {
        FAN(a0, 0) FAN(a1, 1) FAN(a2, 2) FAN(a3, 3)
        FAN(a4, 4) FAN(a5, 5) FAN(a6, 6) FAN(a7, 7)
      } else {
        FAN(b0, 0) FAN(b1, 1) FAN(b2, 2) FAN(b3, 3)
        FAN(b4, 4) FAN(b5, 5) FAN(b6, 6) FAN(b7, 7)
      }
#undef FAN
    }
    __syncthreads();  // h staged; the only full barrier per step

    // prefetch x for next step; hides under dot2 phase
    {
      const int tn = (t < SEQ) ? t : SEQ - 1;
      xp0 = X[(size_t)tn * NIN + l * 2 + 0];
      xp1 = X[(size_t)tn * NIN + l * 2 + 1];
    }

    const uint32_t* hq = hp_lds[par];
    float acc0 = 0.f, acc1 = 0.f, acc2 = 0.f, acc3 = 0.f;
#pragma unroll
    for (int i4 = 0; i4 < 4; ++i4) {
      const int q = (l << 2) | i4;                   // quad of pairs
      const u32x4 hv = *(const u32x4*)&hq[qpos(q) * 4];
#pragma unroll
      for (int jj = 0; jj < 4; ++jj) {
        const int p = i4 * 4 + jj;                   // weight pair index
        acc0 = dot2(whh[0][p], hv[jj], acc0);
        acc1 = dot2(whh[1][p], hv[jj], acc1);
        acc2 = dot2(whh[2][p], hv[jj], acc2);
        acc3 = dot2(whh[3][p], hv[jj], acc3);
      }
    }
    acc0 = fmaf(wih[0][0], x0, acc0); acc0 = fmaf(wih[0][1], x1, acc0);
    acc1 = fmaf(wih[1][0], x0, acc1); acc1 = fmaf(wih[1][1], x1, acc1);
    acc2 = fmaf(wih[2][0], x0, acc2); acc2 = fmaf(wih[2][1], x1, acc2);
    acc3 = fmaf(wih[3][0], x0, acc3); acc3 = fmaf(wih[3][1], x1, acc3);

    acc0 = wave_reduce(acc0);
    acc1 = wave_reduce(acc1);
    acc2 = wave_reduce(acc2);
    acc3 = wave_reduce(acc3);

    if (l == 63) {  // own unit: activations + cell update, post to LDS
      const float i_ = fast_sigmoid(acc0 + bias4[0]);
      const float f_ = fast_sigmoid(acc1 + bias4[1]);
      const float g_ = fast_tanh(acc2 + bias4[2]);
      const float o_ = fast_sigmoid(acc3 + bias4[3]);
      cc = fmaf(f_, cc, i_ * g_);
      const float h = o_ * fast_tanh(cc);
      hl = h;
      pub_lds[w] = ((uint32_t)t << 16) | f32_to_f16lo(h);
    }
    // wave 0: gather 8 posted words (LDS spin), ONE coalesced 32B store.
    if (w == 0 && l < UPB) {
      uint32_t v;
      do { v = pub_lds[l]; } while ((v >> 16) != (uint32_t)t);
      st4_sys(&hslots[(size_t)(t & 1) * HID + blk * UPB + l], v);
    }
  }

  // ---- final head: out = h_last . W_lin + b_lin ----
  if (l == 63) red[w] = hl * wlin;
  __syncthreads();
  if (tid == 0) {
    float s = red[0] + red[1] + red[2] + red[3] +
              red[4] + red[5] + red[6] + red[7];
    uint64_t pv = (uint64_t)__float_as_uint(s) |
                  ((uint64_t)(uint32_t)(SEQ + 1) << 32);
    st8_sys(&fbuf[blk], pv);
  }
  if (blk == 0) {
    if (tid < NBLK) {
      uint64_t v;
      do {
        v = ld8_sys(&fbuf[tid]);
      } while ((uint32_t)(v >> 32) != (uint32_t)(SEQ + 1));
      fin[tid] = __uint_as_float((uint32_t)v);
    }
    __syncthreads();
    if (tid == 0) {
      float s = blin[0];
      for (int i = 0; i < NBLK; ++i) s += fin[i];
      out[0] = s;  // deterministic: fixed summation order, no atomics
    }
  }
}

extern "C" void kernel_launch(void* const* d_in, const int* in_sizes, int n_in,
                              void* d_out, int out_size, void* d_ws,
                              size_t ws_size, hipStream_t stream) {
  const float* X    = (const float*)d_in[0];
  const float* Wih  = (const float*)d_in[1];
  const float* Whh  = (const float*)d_in[2];
  const float* bih  = (const float*)d_in[3];
  const float* bhh  = (const float*)d_in[4];
  const float* Wlin = (const float*)d_in[5];
  const float* blin = (const float*)d_in[6];
  float* out   = (float*)d_out;
  uint32_t* ws = (uint32_t*)d_ws;  // uses 18,432 B (hslots + fbuf)

  void* args[] = {(void*)&X,    (void*)&Wih,  (void*)&Whh,
                  (void*)&bih,  (void*)&bhh,  (void*)&Wlin,
                  (void*)&blin, (void*)&out,  (void*)&ws};
  hipLaunchCooperativeKernel((const void*)lstm_persist, dim3(NBLK), dim3(NTHR),
                             args, 0, stream);
}